// Round 4
// baseline (57.806 us; speedup 1.0000x reference)
//
#include <hip/hip_runtime.h>

// Problem constants (RefCondMul): x[B=4][M=64][L=8192] f32, inds[B][L] int,
// w[1000][64][64] f32, bias[1000][1][64] f32, out[B][64][L] f32.
// out[b][o][l] = sum_m x[b][m][l] * w[inds[b][l]][m][o] + bias[inds[b][l]][0][o]

#define M_DIM 64
#define N_OUTD 64
#define L_DIM 8192
#define TL 16   // samples (l-values) per block

typedef float float4v __attribute__((ext_vector_type(4)));

__global__ __launch_bounds__(256) void condmul_kernel(
    const float* __restrict__ x, const int* __restrict__ inds,
    const float* __restrict__ w, const float* __restrict__ bias,
    float* __restrict__ out) {
  __shared__ float xs[M_DIM][TL];        // 4 KB: x tile, [m][li]
  __shared__ float os[TL][N_OUTD + 4];   // 4.25 KB: output transpose tile (padded)

  const int tid  = threadIdx.x;
  const int wid  = tid >> 6;        // wave id, 0..3
  const int lane = tid & 63;
  const int g    = lane >> 4;       // sample subgroup within wave, 0..3
  const int oi   = (lane & 15) * 4; // this lane's output base (float4)

  const int blk = blockIdx.x;
  const int n0  = blk * TL;         // first global sample id of this block
  const int b   = n0 / L_DIM;
  const int l0  = n0 % L_DIM;       // TL divides L, so whole block shares b

  // ---- stage x tile into LDS: xs[m][li] = x[b][m][l0+li] (coalesced 64B rows)
  {
    const int li = tid & (TL - 1);
    const int m0 = tid >> 4;        // 0..15
    const float* xb = x + ((size_t)b * M_DIM) * L_DIM + l0;
#pragma unroll
    for (int p = 0; p < 4; ++p) {
      const int m = p * 16 + m0;
      xs[m][li] = xb[(size_t)m * L_DIM + li];
    }
  }
  __syncthreads();

  // ---- per-sample matvec: wave serves 4 samples (one per 16-lane group),
  //      each lane owns 4 outputs. Weight rows w[c][m][0..63] are contiguous,
  //      so each group's loads are 256B coalesced segments.
  const int li = wid * 4 + g;           // sample within block, 0..15
  const int c  = inds[n0 + li];         // class index for this sample

  const float* wp = w + ((size_t)c * M_DIM) * N_OUTD + oi;
  float4v acc = {0.f, 0.f, 0.f, 0.f};
#pragma unroll 8
  for (int m = 0; m < M_DIM; ++m) {
    const float  xv = xs[m][li];                                // LDS broadcast
    const float4v wv = *(const float4v*)(wp + (size_t)m * N_OUTD);
    acc += xv * wv;
  }
  acc += *(const float4v*)(bias + (size_t)c * N_OUTD + oi);

  *(float4v*)(&os[li][oi]) = acc;
  __syncthreads();

  // ---- transpose-write: out[b][o][l0+li], 16 consecutive floats per row = 64B lines
  {
    const int lo = tid & (TL - 1);
    const int o0 = tid >> 4;        // 0..15
    float* ob = out + ((size_t)b * N_OUTD) * L_DIM + l0;
#pragma unroll
    for (int p = 0; p < 4; ++p) {
      const int o = p * 16 + o0;
      ob[(size_t)o * L_DIM + lo] = os[lo][o];
    }
  }
}

extern "C" void kernel_launch(void* const* d_in, const int* in_sizes, int n_in,
                              void* d_out, int out_size, void* d_ws, size_t ws_size,
                              hipStream_t stream) {
  const float* x    = (const float*)d_in[0];
  const int*   inds = (const int*)d_in[1];
  const float* w    = (const float*)d_in[2];
  const float* bias = (const float*)d_in[3];
  float*       out  = (float*)d_out;

  const int n_samples = in_sizes[1];     // B * L = 32768
  const int grid = n_samples / TL;       // 2048 blocks
  condmul_kernel<<<grid, 256, 0, stream>>>(x, inds, w, bias, out);
}

// Round 5
// 49.770 us; speedup vs baseline: 1.1615x; 1.1615x over previous
//
#include <hip/hip_runtime.h>

// RefCondMul: x[B=4][64][L=8192] f32, inds[B][L] int, w[1000][64][64] f32,
// bias[1000][1][64] f32 -> out[B][64][L] f32.
// out[b][o][l] = sum_m x[b][m][l] * w[inds[b][l]][m][o] + bias[inds[b][l]][0][o]
//
// Strategy: class-binning. Each w[c] is read from HBM exactly once (16 MB total)
// instead of once per sample (512 MB logical, 183 MB measured fabric traffic in R4).

#define M_DIM 64
#define N_OUTD 64
#define L_DIM 8192
#define B_DIM 4
#define NCLS 1000
#define NSAMP (B_DIM * L_DIM)

typedef float float4v __attribute__((ext_vector_type(4)));

// ---- workspace layout (bytes) ----
#define XT_OFF   0ull            // xt[NSAMP][64] f32         : 8 MB
#define OT_OFF   8388608ull      // ot[NSAMP][64] f32         : 8 MB
#define PERM_OFF 16777216ull     // perm[NSAMP] int           : 128 KB
#define HIST_OFF 16908288ull     // hist[1024] int            : 4 KB
#define CUR_OFF  16912384ull     // cursor[1024] int          : 4 KB (memset with hist)
#define OFFS_OFF 16916480ull     // offsets[1001] int         : ~4 KB
#define WS_NEED  16920592ull

// ======================= kernel A: transpose-in + histogram ==================
// grid 512: one 64m x 64l tile. xt[n][m] = x[b][m][l], n = b*L + l.
__global__ __launch_bounds__(256) void k_tin_hist(
    const float* __restrict__ x, const int* __restrict__ inds,
    float* __restrict__ xt, int* __restrict__ hist) {
  __shared__ float tile[64][68];  // [l][m], padded
  const int tid = threadIdx.x;
  const int b  = blockIdx.x >> 7;
  const int l0 = (blockIdx.x & 127) << 6;

  if (tid < 64) atomicAdd(&hist[inds[b * L_DIM + l0 + tid]], 1);

  const float* xb = x + ((size_t)b * M_DIM) * L_DIM + l0;
  const int r  = tid >> 4;         // 0..15
  const int c4 = (tid & 15) * 4;   // 0..60
#pragma unroll
  for (int p = 0; p < 4; ++p) {
    const int m = r + 16 * p;
    float4v v = *(const float4v*)(xb + (size_t)m * L_DIM + c4);
#pragma unroll
    for (int q = 0; q < 4; ++q) tile[c4 + q][m] = v[q];
  }
  __syncthreads();
  float* xtb = xt + ((size_t)(b * L_DIM + l0)) * M_DIM;
#pragma unroll
  for (int p = 0; p < 4; ++p) {
    const int li = r + 16 * p;
    float4v v = *(const float4v*)(&tile[li][c4]);
    *(float4v*)(xtb + (size_t)li * M_DIM + c4) = v;   // contiguous 16KB region/block
  }
}

// ======================= kernel B: exclusive scan over 1000 bins =============
__global__ __launch_bounds__(1024) void k_scan(
    const int* __restrict__ hist, int* __restrict__ offs) {
  __shared__ int s[1024];
  const int tid = threadIdx.x;
  int v = (tid < NCLS) ? hist[tid] : 0;
  s[tid] = v;
  __syncthreads();
  for (int off = 1; off < 1024; off <<= 1) {
    int t = (tid >= off) ? s[tid - off] : 0;
    __syncthreads();
    s[tid] += t;
    __syncthreads();
  }
  if (tid < NCLS) offs[tid] = s[tid] - v;       // exclusive
  if (tid == NCLS - 1) offs[NCLS] = s[tid];     // total = NSAMP
}

// ======================= kernel C: scatter sample ids into bins ==============
__global__ __launch_bounds__(256) void k_scatter(
    const int* __restrict__ inds, const int* __restrict__ offs,
    int* __restrict__ cur, int* __restrict__ perm) {
  const int n = blockIdx.x * 256 + threadIdx.x;
  const int c = inds[n];
  const int pos = offs[c] + atomicAdd(&cur[c], 1);
  perm[pos] = n;
}

// ======================= kernel D: binned matvec, w[c] in LDS ================
// grid = 1000 (one block per class). 16 samples per iteration; each 16-lane
// group owns one sample, each lane owns 4 outputs (float4).
__global__ __launch_bounds__(256) void k_main(
    const float* __restrict__ xt, const int* __restrict__ perm,
    const int* __restrict__ offs, const float* __restrict__ w,
    const float* __restrict__ bias, float* __restrict__ ot) {
  __shared__ float wl[4096];        // w[c]: 16 KB
  __shared__ float xs[16][68];      // 16 samples' x, padded rows
  __shared__ int   ns[16];

  const int tid = threadIdx.x;
  const int c   = blockIdx.x;
  const int start = offs[c];
  const int count = offs[c + 1] - start;

  // stage w[c] into LDS (coalesced: wave reads 1KB contiguous per inst)
  const float* wp = w + (size_t)c * (M_DIM * N_OUTD);
#pragma unroll
  for (int p = 0; p < 4; ++p) {
    const int idx = (p * 256 + tid) * 4;
    *(float4v*)(&wl[idx]) = *(const float4v*)(wp + idx);
  }

  const int wid  = tid >> 6;
  const int lane = tid & 63;
  const int g    = lane >> 4;
  const int oi   = (lane & 15) * 4;
  const int j    = wid * 4 + g;          // compute: sample slot 0..15
  const int sj   = tid >> 4;             // staging: sample slot 0..15
  const int smi  = (tid & 15) * 4;       // staging: m base

  const float4v bv = *(const float4v*)(bias + (size_t)c * N_OUTD + oi);
  __syncthreads();  // wl ready

  for (int s0 = 0; s0 < count; s0 += 16) {
    if (s0 + sj < count) {
      const int n = perm[start + s0 + sj];
      *(float4v*)(&xs[sj][smi]) = *(const float4v*)(xt + (size_t)n * M_DIM + smi);
      if (smi == 0) ns[sj] = n;
    }
    __syncthreads();
    if (s0 + j < count) {
      float4v acc = bv;
#pragma unroll
      for (int m = 0; m < M_DIM; ++m) {
        const float4v wv = *(const float4v*)(&wl[m * N_OUTD + oi]);
        acc += xs[j][m] * wv;
      }
      const int n = ns[j];
      *(float4v*)(ot + (size_t)n * N_OUTD + oi) = acc;  // 256B contiguous/group
    }
    __syncthreads();
  }
}

// ======================= kernel E: transpose-out =============================
// out[b][o][l] = ot[b*L+l][o]; grid 512, one 64o x 64l tile.
__global__ __launch_bounds__(256) void k_tout(
    const float* __restrict__ ot, float* __restrict__ out) {
  __shared__ float tile[64][68];  // [o][l], padded
  const int tid = threadIdx.x;
  const int b  = blockIdx.x >> 7;
  const int l0 = (blockIdx.x & 127) << 6;

  const float* otb = ot + ((size_t)(b * L_DIM + l0)) * N_OUTD;
  const int r  = tid >> 4;
  const int c4 = (tid & 15) * 4;
#pragma unroll
  for (int p = 0; p < 4; ++p) {
    const int li = r + 16 * p;
    float4v v = *(const float4v*)(otb + (size_t)li * N_OUTD + c4);  // contiguous
#pragma unroll
    for (int q = 0; q < 4; ++q) tile[c4 + q][li] = v[q];
  }
  __syncthreads();
  float* ob = out + ((size_t)b * N_OUTD) * L_DIM + l0;
#pragma unroll
  for (int p = 0; p < 4; ++p) {
    const int o = r + 16 * p;
    float4v v = *(const float4v*)(&tile[o][c4]);
    *(float4v*)(ob + (size_t)o * L_DIM + c4) = v;  // 64B-line writes
  }
}

// ======================= fallback (R4 kernel) if ws too small ================
#define TL 16
__global__ __launch_bounds__(256) void condmul_fallback(
    const float* __restrict__ x, const int* __restrict__ inds,
    const float* __restrict__ w, const float* __restrict__ bias,
    float* __restrict__ out) {
  __shared__ float xs[M_DIM][TL];
  __shared__ float os[TL][N_OUTD + 4];
  const int tid  = threadIdx.x;
  const int wid  = tid >> 6;
  const int lane = tid & 63;
  const int g    = lane >> 4;
  const int oi   = (lane & 15) * 4;
  const int n0   = blockIdx.x * TL;
  const int b    = n0 / L_DIM;
  const int l0   = n0 % L_DIM;
  {
    const int li = tid & (TL - 1);
    const int m0 = tid >> 4;
    const float* xb = x + ((size_t)b * M_DIM) * L_DIM + l0;
#pragma unroll
    for (int p = 0; p < 4; ++p) {
      const int m = p * 16 + m0;
      xs[m][li] = xb[(size_t)m * L_DIM + li];
    }
  }
  __syncthreads();
  const int li = wid * 4 + g;
  const int c  = inds[n0 + li];
  const float* wp = w + ((size_t)c * M_DIM) * N_OUTD + oi;
  float4v acc = {0.f, 0.f, 0.f, 0.f};
#pragma unroll 8
  for (int m = 0; m < M_DIM; ++m) {
    const float  xv = xs[m][li];
    const float4v wv = *(const float4v*)(wp + (size_t)m * N_OUTD);
    acc += xv * wv;
  }
  acc += *(const float4v*)(bias + (size_t)c * N_OUTD + oi);
  *(float4v*)(&os[li][oi]) = acc;
  __syncthreads();
  {
    const int lo = tid & (TL - 1);
    const int o0 = tid >> 4;
    float* ob = out + ((size_t)b * N_OUTD) * L_DIM + l0;
#pragma unroll
    for (int p = 0; p < 4; ++p) {
      const int o = p * 16 + o0;
      ob[(size_t)o * L_DIM + lo] = os[lo][o];
    }
  }
}

extern "C" void kernel_launch(void* const* d_in, const int* in_sizes, int n_in,
                              void* d_out, int out_size, void* d_ws, size_t ws_size,
                              hipStream_t stream) {
  const float* x    = (const float*)d_in[0];
  const int*   inds = (const int*)d_in[1];
  const float* w    = (const float*)d_in[2];
  const float* bias = (const float*)d_in[3];
  float*       out  = (float*)d_out;

  if (ws_size < WS_NEED) {
    condmul_fallback<<<NSAMP / TL, 256, 0, stream>>>(x, inds, w, bias, out);
    return;
  }

  char* ws = (char*)d_ws;
  float* xt   = (float*)(ws + XT_OFF);
  float* ot   = (float*)(ws + OT_OFF);
  int*   perm = (int*)(ws + PERM_OFF);
  int*   hist = (int*)(ws + HIST_OFF);
  int*   cur  = (int*)(ws + CUR_OFF);
  int*   offs = (int*)(ws + OFFS_OFF);

  // zero hist + cursor every call (ws is NOT re-poisoned between replays)
  hipMemsetAsync(ws + HIST_OFF, 0, 8192, stream);

  k_tin_hist<<<512, 256, 0, stream>>>(x, inds, xt, hist);
  k_scan<<<1, 1024, 0, stream>>>(hist, offs);
  k_scatter<<<NSAMP / 256, 256, 0, stream>>>(inds, offs, cur, perm);
  k_main<<<NCLS, 256, 0, stream>>>(xt, perm, offs, w, bias, ot);
  k_tout<<<512, 256, 0, stream>>>(ot, out);
}

// Round 6
// 49.267 us; speedup vs baseline: 1.1733x; 1.0102x over previous
//
#include <hip/hip_runtime.h>

// RefCondMul: x[B=4][64][L=8192] f32, inds[B][L] int, w[1000][64][64] f32,
// bias[1000][1][64] f32 -> out[B][64][L] f32.
// out[b][o][l] = sum_m x[b][m][l] * w[inds[b][l]][m][o] + bias[inds[b][l]][0][o]
//
// Strategy: class-binning. Each w[c] is read from HBM exactly once (16 MB total)
// instead of once per sample (512 MB logical; R4 measured 183 MB fabric traffic).
// R5 lesson: hipMemsetAsync(8KB) cost 42.6us of the 49.8us total (rocclr
// fillBufferAligned pathology) -> replaced with a 1-block zero kernel.

#define M_DIM 64
#define N_OUTD 64
#define L_DIM 8192
#define B_DIM 4
#define NCLS 1000
#define NSAMP (B_DIM * L_DIM)

typedef float float4v __attribute__((ext_vector_type(4)));
typedef int   int4v   __attribute__((ext_vector_type(4)));

// ---- workspace layout (bytes) ----
#define XT_OFF   0ull            // xt[NSAMP][64] f32         : 8 MB
#define OT_OFF   8388608ull      // ot[NSAMP][64] f32         : 8 MB
#define PERM_OFF 16777216ull     // perm[NSAMP] int           : 128 KB
#define HIST_OFF 16908288ull     // hist[1024] int            : 4 KB
#define CUR_OFF  16912384ull     // cursor[1024] int          : 4 KB (written by k_scan)
#define OFFS_OFF 16916480ull     // offsets[1001] int         : ~4 KB
#define WS_NEED  16920592ull

// ======================= kernel Z: zero the histogram ========================
__global__ __launch_bounds__(256) void k_zero(int* __restrict__ hist) {
  ((int4v*)hist)[threadIdx.x] = (int4v){0, 0, 0, 0};  // 256*16B = 4KB
}

// ======================= kernel A: transpose-in + histogram ==================
// grid 512: one 64m x 64l tile. xt[n][m] = x[b][m][l], n = b*L + l.
__global__ __launch_bounds__(256) void k_tin_hist(
    const float* __restrict__ x, const int* __restrict__ inds,
    float* __restrict__ xt, int* __restrict__ hist) {
  __shared__ float tile[64][68];  // [l][m], padded
  const int tid = threadIdx.x;
  const int b  = blockIdx.x >> 7;
  const int l0 = (blockIdx.x & 127) << 6;

  if (tid < 64) atomicAdd(&hist[inds[b * L_DIM + l0 + tid]], 1);

  const float* xb = x + ((size_t)b * M_DIM) * L_DIM + l0;
  const int r  = tid >> 4;         // 0..15
  const int c4 = (tid & 15) * 4;   // 0..60
#pragma unroll
  for (int p = 0; p < 4; ++p) {
    const int m = r + 16 * p;
    float4v v = *(const float4v*)(xb + (size_t)m * L_DIM + c4);
#pragma unroll
    for (int q = 0; q < 4; ++q) tile[c4 + q][m] = v[q];
  }
  __syncthreads();
  float* xtb = xt + ((size_t)(b * L_DIM + l0)) * M_DIM;
#pragma unroll
  for (int p = 0; p < 4; ++p) {
    const int li = r + 16 * p;
    float4v v = *(const float4v*)(&tile[li][c4]);
    *(float4v*)(xtb + (size_t)li * M_DIM + c4) = v;   // contiguous 16KB region/block
  }
}

// ======================= kernel B: exclusive scan over 1000 bins =============
// Writes offs[0..NCLS] and a working copy cur[] for the scatter's atomics.
__global__ __launch_bounds__(1024) void k_scan(
    const int* __restrict__ hist, int* __restrict__ offs, int* __restrict__ cur) {
  __shared__ int s[1024];
  const int tid = threadIdx.x;
  int v = (tid < NCLS) ? hist[tid] : 0;
  s[tid] = v;
  __syncthreads();
  for (int off = 1; off < 1024; off <<= 1) {
    int t = (tid >= off) ? s[tid - off] : 0;
    __syncthreads();
    s[tid] += t;
    __syncthreads();
  }
  if (tid < NCLS) {
    const int excl = s[tid] - v;
    offs[tid] = excl;
    cur[tid]  = excl;
  }
  if (tid == NCLS - 1) offs[NCLS] = s[tid];     // total = NSAMP
}

// ======================= kernel C: scatter sample ids into bins ==============
__global__ __launch_bounds__(256) void k_scatter(
    const int* __restrict__ inds, int* __restrict__ cur, int* __restrict__ perm) {
  const int n = blockIdx.x * 256 + threadIdx.x;
  const int pos = atomicAdd(&cur[inds[n]], 1);
  perm[pos] = n;
}

// ======================= kernel D: binned matvec, w[c] in LDS ================
// grid = 1000 (one block per class). 16 samples per iteration; each 16-lane
// group owns one sample, each lane owns 4 outputs (float4).
__global__ __launch_bounds__(256) void k_main(
    const float* __restrict__ xt, const int* __restrict__ perm,
    const int* __restrict__ offs, const float* __restrict__ w,
    const float* __restrict__ bias, float* __restrict__ ot) {
  __shared__ float wl[4096];        // w[c]: 16 KB
  __shared__ float xs[16][68];      // 16 samples' x, padded rows
  __shared__ int   ns[16];

  const int tid = threadIdx.x;
  const int c   = blockIdx.x;
  const int start = offs[c];
  const int count = offs[c + 1] - start;

  // stage w[c] into LDS (coalesced: wave reads 1KB contiguous per inst)
  const float* wp = w + (size_t)c * (M_DIM * N_OUTD);
#pragma unroll
  for (int p = 0; p < 4; ++p) {
    const int idx = (p * 256 + tid) * 4;
    *(float4v*)(&wl[idx]) = *(const float4v*)(wp + idx);
  }

  const int wid  = tid >> 6;
  const int lane = tid & 63;
  const int g    = lane >> 4;
  const int oi   = (lane & 15) * 4;
  const int j    = wid * 4 + g;          // compute: sample slot 0..15
  const int sj   = tid >> 4;             // staging: sample slot 0..15
  const int smi  = (tid & 15) * 4;       // staging: m base

  const float4v bv = *(const float4v*)(bias + (size_t)c * N_OUTD + oi);
  __syncthreads();  // wl ready

  for (int s0 = 0; s0 < count; s0 += 16) {
    if (s0 + sj < count) {
      const int n = perm[start + s0 + sj];
      *(float4v*)(&xs[sj][smi]) = *(const float4v*)(xt + (size_t)n * M_DIM + smi);
      if (smi == 0) ns[sj] = n;
    }
    __syncthreads();
    if (s0 + j < count) {
      float4v acc = bv;
#pragma unroll
      for (int m = 0; m < M_DIM; ++m) {
        const float4v wv = *(const float4v*)(&wl[m * N_OUTD + oi]);
        acc += xs[j][m] * wv;
      }
      const int n = ns[j];
      *(float4v*)(ot + (size_t)n * N_OUTD + oi) = acc;  // 256B contiguous/group
    }
    __syncthreads();
  }
}

// ======================= kernel E: transpose-out =============================
// out[b][o][l] = ot[b*L+l][o]; grid 512, one 64o x 64l tile.
__global__ __launch_bounds__(256) void k_tout(
    const float* __restrict__ ot, float* __restrict__ out) {
  __shared__ float tile[64][68];  // [o][l], padded
  const int tid = threadIdx.x;
  const int b  = blockIdx.x >> 7;
  const int l0 = (blockIdx.x & 127) << 6;

  const float* otb = ot + ((size_t)(b * L_DIM + l0)) * N_OUTD;
  const int r  = tid >> 4;
  const int c4 = (tid & 15) * 4;
#pragma unroll
  for (int p = 0; p < 4; ++p) {
    const int li = r + 16 * p;
    float4v v = *(const float4v*)(otb + (size_t)li * N_OUTD + c4);  // contiguous
#pragma unroll
    for (int q = 0; q < 4; ++q) tile[c4 + q][li] = v[q];
  }
  __syncthreads();
  float* ob = out + ((size_t)b * N_OUTD) * L_DIM + l0;
#pragma unroll
  for (int p = 0; p < 4; ++p) {
    const int o = r + 16 * p;
    float4v v = *(const float4v*)(&tile[o][c4]);
    *(float4v*)(ob + (size_t)o * L_DIM + c4) = v;  // 64B-line writes
  }
}

// ======================= fallback (R4 kernel) if ws too small ================
#define TL 16
__global__ __launch_bounds__(256) void condmul_fallback(
    const float* __restrict__ x, const int* __restrict__ inds,
    const float* __restrict__ w, const float* __restrict__ bias,
    float* __restrict__ out) {
  __shared__ float xs[M_DIM][TL];
  __shared__ float os[TL][N_OUTD + 4];
  const int tid  = threadIdx.x;
  const int wid  = tid >> 6;
  const int lane = tid & 63;
  const int g    = lane >> 4;
  const int oi   = (lane & 15) * 4;
  const int n0   = blockIdx.x * TL;
  const int b    = n0 / L_DIM;
  const int l0   = n0 % L_DIM;
  {
    const int li = tid & (TL - 1);
    const int m0 = tid >> 4;
    const float* xb = x + ((size_t)b * M_DIM) * L_DIM + l0;
#pragma unroll
    for (int p = 0; p < 4; ++p) {
      const int m = p * 16 + m0;
      xs[m][li] = xb[(size_t)m * L_DIM + li];
    }
  }
  __syncthreads();
  const int li = wid * 4 + g;
  const int c  = inds[n0 + li];
  const float* wp = w + ((size_t)c * M_DIM) * N_OUTD + oi;
  float4v acc = {0.f, 0.f, 0.f, 0.f};
#pragma unroll 8
  for (int m = 0; m < M_DIM; ++m) {
    const float  xv = xs[m][li];
    const float4v wv = *(const float4v*)(wp + (size_t)m * N_OUTD);
    acc += xv * wv;
  }
  acc += *(const float4v*)(bias + (size_t)c * N_OUTD + oi);
  *(float4v*)(&os[li][oi]) = acc;
  __syncthreads();
  {
    const int lo = tid & (TL - 1);
    const int o0 = tid >> 4;
    float* ob = out + ((size_t)b * N_OUTD) * L_DIM + l0;
#pragma unroll
    for (int p = 0; p < 4; ++p) {
      const int o = p * 16 + o0;
      ob[(size_t)o * L_DIM + lo] = os[lo][o];
    }
  }
}

extern "C" void kernel_launch(void* const* d_in, const int* in_sizes, int n_in,
                              void* d_out, int out_size, void* d_ws, size_t ws_size,
                              hipStream_t stream) {
  const float* x    = (const float*)d_in[0];
  const int*   inds = (const int*)d_in[1];
  const float* w    = (const float*)d_in[2];
  const float* bias = (const float*)d_in[3];
  float*       out  = (float*)d_out;

  if (ws_size < WS_NEED) {
    condmul_fallback<<<NSAMP / TL, 256, 0, stream>>>(x, inds, w, bias, out);
    return;
  }

  char* ws = (char*)d_ws;
  float* xt   = (float*)(ws + XT_OFF);
  float* ot   = (float*)(ws + OT_OFF);
  int*   perm = (int*)(ws + PERM_OFF);
  int*   hist = (int*)(ws + HIST_OFF);
  int*   cur  = (int*)(ws + CUR_OFF);
  int*   offs = (int*)(ws + OFFS_OFF);

  k_zero<<<1, 256, 0, stream>>>(hist);
  k_tin_hist<<<512, 256, 0, stream>>>(x, inds, xt, hist);
  k_scan<<<1, 1024, 0, stream>>>(hist, offs, cur);
  k_scatter<<<NSAMP / 256, 256, 0, stream>>>(inds, cur, perm);
  k_main<<<NCLS, 256, 0, stream>>>(xt, perm, offs, w, bias, ot);
  k_tout<<<512, 256, 0, stream>>>(ot, out);
}